// Round 11
// baseline (72.325 us; speedup 1.0000x reference)
//
#include <hip/hip_runtime.h>

#define B_  32
#define H_  512
#define W_  512
#define HW_ (H_ * W_)
#define NBLK_ 2048             // 2048 blocks * 4 waves = 8192 waves = 32 img * 256 row-pairs
#define TPB_  256

typedef float f32x4 __attribute__((ext_vector_type(4)));

__device__ __forceinline__ float rcp_fast(float x) { return __builtin_amdgcn_rcpf(x); }

// WENO3, single fast-rcp form (validated rounds 1-10, absmax 0.0)
__device__ __forceinline__ float weno_minus(float vmm, float vm, float vp) {
    float d0 = vmm - vm, d1 = vm - vp;
    float t0 = 1e-6f + d0 * d0;
    float t1 = 1e-6f + d1 * d1;
    float s0 = t0 * t0, s1 = t1 * t1;
    float s0x2 = s0 + s0;
    float p0 = 1.5f * vm - 0.5f * vmm;
    float p1 = 0.5f * (vm + vp);
    return (s1 * p0 + s0x2 * p1) * rcp_fast(s1 + s0x2);
}

__device__ __forceinline__ float weno_plus(float vmm, float vm, float vp) {
    float d0 = vp - vm, d1 = vm - vmm;
    float t0 = 1e-6f + d0 * d0;
    float t1 = 1e-6f + d1 * d1;
    float s0 = t0 * t0, s1 = t1 * t1;
    float s0x2 = s0 + s0;
    float p0 = 1.5f * vm - 0.5f * vp;
    float p1 = 0.5f * (vm + vmm);
    return (s1 * p0 + s0x2 * p1) * rcp_fast(s1 + s0x2);
}

__device__ __forceinline__ void pixel_eval(
        float vxmm, float vxm, float vxc, float vxp,
        float vymm, float vym, float vyc, float vyp,
        float rh, float target, float lo, float hi,
        float& num, float& den) {
    float ux_minus = weno_minus(vxmm, vxm, vxc);
    float ux_plus  = weno_plus(vxm, vxc, vxp);
    float gx = fmaxf(fmaxf(ux_minus, -ux_plus), 0.0f);

    float uy_minus = weno_minus(vymm, vym, vyc);
    float uy_plus  = weno_plus(vym, vyc, vyp);
    float gy = fmaxf(fmaxf(uy_minus, -uy_plus), 0.0f);

    float gmag = __builtin_amdgcn_sqrtf(gx * gx + gy * gy + 1e-8f);

    float residual = gmag - target;
    float ar = fabsf(residual);
    float per_pixel = (ar < 0.01f) ? (50.0f * residual * residual)
                                   : (ar - 0.005f);

    bool m = (rh > 0.5f) && (gmag >= lo) && (gmag <= hi);
    float sel = m ? 1.0f : 0.0f;
    num = fmaf(sel, per_pixel, num);
    den += sel;
}

// One full row (8 px/lane). y-direction differences are passed in (shared
// between the two rows this wave owns).
__device__ __forceinline__ void row_eval(
        f32x4 c0, f32x4 c1,
        f32x4 ymm0, f32x4 ymm1,   // v_mm = row(y-1) - row(y-2)
        f32x4 ym0,  f32x4 ym1,    // v_m  = row(y)   - row(y-1)
        f32x4 yc0,  f32x4 yc1,    // v_c  = row(y+1) - row(y)
        f32x4 yp0,  f32x4 yp1,    // v_p  = row(y+2) - row(y+1)
        f32x4 q0, f32x4 q1,
        int lane, float target, float lo, float hi,
        float& num, float& den) {
    float xm2 = __shfl_up(c1.z, 1);
    float xm1 = __shfl_up(c1.w, 1);
    float xp1 = __shfl_down(c0.x, 1);
    float xp2 = __shfl_down(c0.y, 1);
    if (lane == 0)  { xm2 = c0.x; xm1 = c0.x; }
    if (lane == 63) { xp1 = c1.w; xp2 = c1.w; }

    float D0  = xm1 - xm2;
    float D1  = c0.x - xm1;
    float D2  = c0.y - c0.x;
    float D3  = c0.z - c0.y;
    float D4  = c0.w - c0.z;
    float D5  = c1.x - c0.w;
    float D6  = c1.y - c1.x;
    float D7  = c1.z - c1.y;
    float D8  = c1.w - c1.z;
    float D9  = xp1 - c1.w;
    float D10 = xp2 - xp1;

    pixel_eval(D0, D1, D2, D3,  ymm0.x, ym0.x, yc0.x, yp0.x,
               q0.x, target, lo, hi, num, den);
    pixel_eval(D1, D2, D3, D4,  ymm0.y, ym0.y, yc0.y, yp0.y,
               q0.y, target, lo, hi, num, den);
    pixel_eval(D2, D3, D4, D5,  ymm0.z, ym0.z, yc0.z, yp0.z,
               q0.z, target, lo, hi, num, den);
    pixel_eval(D3, D4, D5, D6,  ymm0.w, ym0.w, yc0.w, yp0.w,
               q0.w, target, lo, hi, num, den);
    pixel_eval(D4, D5, D6, D7,  ymm1.x, ym1.x, yc1.x, yp1.x,
               q1.x, target, lo, hi, num, den);
    pixel_eval(D5, D6, D7, D8,  ymm1.y, ym1.y, yc1.y, yp1.y,
               q1.y, target, lo, hi, num, den);
    pixel_eval(D6, D7, D8, D9,  ymm1.z, ym1.z, yc1.z, yp1.z,
               q1.z, target, lo, hi, num, den);
    pixel_eval(D7, D8, D9, D10, ymm1.w, ym1.w, yc1.w, yp1.w,
               q1.w, target, lo, hi, num, den);
}

__device__ __forceinline__ int clampy(int v) {
    return v < 0 ? 0 : (v > H_ - 1 ? H_ - 1 : v);
}

__global__ __launch_bounds__(TPB_) void eikonal_main(
        const float* __restrict__ pred, const float* __restrict__ reach,
        unsigned* __restrict__ counter, double2* __restrict__ partials,
        float* __restrict__ out) {
    const float target = 1.0f / sqrtf((float)(511 * 511 + 511 * 511));
    const float lo = 0.3f * target;
    const float hi = 5.0f * target;

    int t = threadIdx.x;
    int lane = t & 63;

    // XCD-bijective swizzle (2048 % 8 == 0): neighboring row-pairs share halo
    // rows -> same XCD L2.
    int bswz = ((blockIdx.x & 7) << 8) + (blockIdx.x >> 3);
    // wave-uniform id -> all row addressing is SALU
    int wv = __builtin_amdgcn_readfirstlane((bswz << 2) + (t >> 6)); // 0..8191
    int b  = wv >> 8;            // image
    int y0 = (wv & 255) << 1;    // even row; wave owns rows y0, y0+1

    const float* brow = pred + b * HW_;
    int x0 = lane << 3;          // 8 px per lane

    const float* rA = brow + (clampy(y0 - 2) << 9) + x0;
    const float* rB = brow + (clampy(y0 - 1) << 9) + x0;
    const float* rC = brow + ((y0    ) << 9) + x0;
    const float* rD = brow + ((y0 + 1) << 9) + x0;
    const float* rE = brow + (clampy(y0 + 2) << 9) + x0;
    const float* rF = brow + (clampy(y0 + 3) << 9) + x0;
    const float* qC = reach + b * HW_ + ((y0    ) << 9) + x0;
    const float* qD = reach + b * HW_ + ((y0 + 1) << 9) + x0;

    // ---- issue all 16 loads (r9-validated width: no spill) ----
    f32x4 pA0 = *(const f32x4*)(rA);     f32x4 pA1 = *(const f32x4*)(rA + 4);
    f32x4 pB0 = *(const f32x4*)(rB);     f32x4 pB1 = *(const f32x4*)(rB + 4);
    f32x4 pC0 = *(const f32x4*)(rC);     f32x4 pC1 = *(const f32x4*)(rC + 4);
    f32x4 pD0 = *(const f32x4*)(rD);     f32x4 pD1 = *(const f32x4*)(rD + 4);
    f32x4 pE0 = *(const f32x4*)(rE);     f32x4 pE1 = *(const f32x4*)(rE + 4);
    f32x4 pF0 = *(const f32x4*)(rF);     f32x4 pF1 = *(const f32x4*)(rF + 4);
    f32x4 qC0 = *(const f32x4*)(qC);     f32x4 qC1 = *(const f32x4*)(qC + 4);
    f32x4 qD0 = *(const f32x4*)(qD);     f32x4 qD1 = *(const f32x4*)(qD + 4);

    // Pin all 16 loads live here: prevents regalloc from sinking loads to
    // uses; all issued before one wait point (r9: -13%).
    asm volatile("" ::
        "v"(pA0), "v"(pA1), "v"(pB0), "v"(pB1),
        "v"(pC0), "v"(pC1), "v"(pD0), "v"(pD1),
        "v"(pE0), "v"(pE1), "v"(pF0), "v"(pF1),
        "v"(qC0), "v"(qC1), "v"(qD0), "v"(qD1));
    __builtin_amdgcn_sched_barrier(0);

    // ---- shared y forward differences (5 pairs instead of 8) ----
    f32x4 dBA0 = pB0 - pA0, dBA1 = pB1 - pA1;
    f32x4 dCB0 = pC0 - pB0, dCB1 = pC1 - pB1;
    f32x4 dDC0 = pD0 - pC0, dDC1 = pD1 - pC1;
    f32x4 dED0 = pE0 - pD0, dED1 = pE1 - pD1;
    f32x4 dFE0 = pF0 - pE0, dFE1 = pF1 - pE1;

    float num = 0.0f, den = 0.0f;

    // row C: ymm=dBA, ym=dCB, yc=dDC, yp=dED
    row_eval(pC0, pC1, dBA0, dBA1, dCB0, dCB1, dDC0, dDC1, dED0, dED1,
             qC0, qC1, lane, target, lo, hi, num, den);
    // row D: ymm=dCB, ym=dDC, yc=dED, yp=dFE
    row_eval(pD0, pD1, dCB0, dCB1, dDC0, dDC1, dED0, dED1, dFE0, dFE1,
             qD0, qD1, lane, target, lo, hi, num, den);

    // ---- block reduction (4 waves) ----
    double dn = (double)num;
    double dd = (double)den;
    #pragma unroll
    for (int off = 32; off > 0; off >>= 1) {
        dn += __shfl_down(dn, off);
        dd += __shfl_down(dd, off);
    }
    __shared__ double sn[4], sd[4];
    __shared__ int last_flag;
    int wid = t >> 6;
    if (lane == 0) { sn[wid] = dn; sd[wid] = dd; }
    __syncthreads();
    if (t == 0) {
        double2 p;
        p.x = sn[0] + sn[1] + sn[2] + sn[3];
        p.y = sd[0] + sd[1] + sd[2] + sd[3];
        partials[blockIdx.x] = p;
        __threadfence();                       // publish partial (device scope)
        unsigned prev = atomicAdd(counter, 1u);
        last_flag = (prev == NBLK_ - 1) ? 1 : 0;
    }
    __syncthreads();

    // ---- last finishing block reduces all partials (fused finalize) ----
    if (last_flag) {
        __threadfence();                       // acquire all partials
        double n = 0.0, d = 0.0;
        #pragma unroll
        for (int k = 0; k < NBLK_ / TPB_; ++k) {
            double2 p = partials[t + (k << 8)];
            n += p.x;
            d += p.y;
        }
        #pragma unroll
        for (int off = 32; off > 0; off >>= 1) {
            n += __shfl_down(n, off);
            d += __shfl_down(d, off);
        }
        if (lane == 0) { sn[wid] = n; sd[wid] = d; }
        __syncthreads();
        if (t == 0) {
            double fn = sn[0] + sn[1] + sn[2] + sn[3];
            double fd = sd[0] + sd[1] + sd[2] + sd[3];
            if (fd < 1e-8) fd = 1e-8;
            out[0] = (float)(fn / fd);
        }
    }
}

extern "C" void kernel_launch(void* const* d_in, const int* in_sizes, int n_in,
                              void* d_out, int out_size, void* d_ws, size_t ws_size,
                              hipStream_t stream) {
    const float* pred  = (const float*)d_in[0];
    const float* reach = (const float*)d_in[1];
    float* out = (float*)d_out;

    // d_ws layout: [0,64): atomic counter (zeroed each call); [64, ...): partials
    unsigned* counter = (unsigned*)d_ws;
    double2* partials = (double2*)((char*)d_ws + 64);

    hipMemsetAsync(d_ws, 0, 64, stream);
    eikonal_main<<<NBLK_, TPB_, 0, stream>>>(pred, reach, counter, partials, out);
}

// Round 12
// 31.732 us; speedup vs baseline: 2.2792x; 2.2792x over previous
//
#include <hip/hip_runtime.h>

#define B_  32
#define H_  512
#define W_  512
#define HW_ (H_ * W_)
#define NBLK_ 2048             // 2048 blocks * 4 waves = 8192 waves = 32 img * 256 row-pairs
#define TPB_  256

typedef float f32x4 __attribute__((ext_vector_type(4)));

__device__ __forceinline__ float rcp_fast(float x) { return __builtin_amdgcn_rcpf(x); }

// WENO3, single fast-rcp form (validated rounds 1-11, absmax 0.0)
__device__ __forceinline__ float weno_minus(float vmm, float vm, float vp) {
    float d0 = vmm - vm, d1 = vm - vp;
    float t0 = 1e-6f + d0 * d0;
    float t1 = 1e-6f + d1 * d1;
    float s0 = t0 * t0, s1 = t1 * t1;
    float s0x2 = s0 + s0;
    float p0 = 1.5f * vm - 0.5f * vmm;
    float p1 = 0.5f * (vm + vp);
    return (s1 * p0 + s0x2 * p1) * rcp_fast(s1 + s0x2);
}

__device__ __forceinline__ float weno_plus(float vmm, float vm, float vp) {
    float d0 = vp - vm, d1 = vm - vmm;
    float t0 = 1e-6f + d0 * d0;
    float t1 = 1e-6f + d1 * d1;
    float s0 = t0 * t0, s1 = t1 * t1;
    float s0x2 = s0 + s0;
    float p0 = 1.5f * vm - 0.5f * vp;
    float p1 = 0.5f * (vm + vmm);
    return (s1 * p0 + s0x2 * p1) * rcp_fast(s1 + s0x2);
}

__device__ __forceinline__ void pixel_eval(
        float vxmm, float vxm, float vxc, float vxp,
        float vymm, float vym, float vyc, float vyp,
        float rh, float target, float lo, float hi,
        float& num, float& den) {
    float ux_minus = weno_minus(vxmm, vxm, vxc);
    float ux_plus  = weno_plus(vxm, vxc, vxp);
    float gx = fmaxf(fmaxf(ux_minus, -ux_plus), 0.0f);

    float uy_minus = weno_minus(vymm, vym, vyc);
    float uy_plus  = weno_plus(vym, vyc, vyp);
    float gy = fmaxf(fmaxf(uy_minus, -uy_plus), 0.0f);

    float gmag = __builtin_amdgcn_sqrtf(gx * gx + gy * gy + 1e-8f);

    float residual = gmag - target;
    float ar = fabsf(residual);
    float per_pixel = (ar < 0.01f) ? (50.0f * residual * residual)
                                   : (ar - 0.005f);

    bool m = (rh > 0.5f) && (gmag >= lo) && (gmag <= hi);
    float sel = m ? 1.0f : 0.0f;
    num = fmaf(sel, per_pixel, num);
    den += sel;
}

// One full row (8 px/lane). y-direction differences passed in (shared
// between the two rows this wave owns).
__device__ __forceinline__ void row_eval(
        f32x4 c0, f32x4 c1,
        f32x4 ymm0, f32x4 ymm1,
        f32x4 ym0,  f32x4 ym1,
        f32x4 yc0,  f32x4 yc1,
        f32x4 yp0,  f32x4 yp1,
        f32x4 q0, f32x4 q1,
        int lane, float target, float lo, float hi,
        float& num, float& den) {
    float xm2 = __shfl_up(c1.z, 1);
    float xm1 = __shfl_up(c1.w, 1);
    float xp1 = __shfl_down(c0.x, 1);
    float xp2 = __shfl_down(c0.y, 1);
    if (lane == 0)  { xm2 = c0.x; xm1 = c0.x; }
    if (lane == 63) { xp1 = c1.w; xp2 = c1.w; }

    float D0  = xm1 - xm2;
    float D1  = c0.x - xm1;
    float D2  = c0.y - c0.x;
    float D3  = c0.z - c0.y;
    float D4  = c0.w - c0.z;
    float D5  = c1.x - c0.w;
    float D6  = c1.y - c1.x;
    float D7  = c1.z - c1.y;
    float D8  = c1.w - c1.z;
    float D9  = xp1 - c1.w;
    float D10 = xp2 - xp1;

    pixel_eval(D0, D1, D2, D3,  ymm0.x, ym0.x, yc0.x, yp0.x,
               q0.x, target, lo, hi, num, den);
    pixel_eval(D1, D2, D3, D4,  ymm0.y, ym0.y, yc0.y, yp0.y,
               q0.y, target, lo, hi, num, den);
    pixel_eval(D2, D3, D4, D5,  ymm0.z, ym0.z, yc0.z, yp0.z,
               q0.z, target, lo, hi, num, den);
    pixel_eval(D3, D4, D5, D6,  ymm0.w, ym0.w, yc0.w, yp0.w,
               q0.w, target, lo, hi, num, den);
    pixel_eval(D4, D5, D6, D7,  ymm1.x, ym1.x, yc1.x, yp1.x,
               q1.x, target, lo, hi, num, den);
    pixel_eval(D5, D6, D7, D8,  ymm1.y, ym1.y, yc1.y, yp1.y,
               q1.y, target, lo, hi, num, den);
    pixel_eval(D6, D7, D8, D9,  ymm1.z, ym1.z, yc1.z, yp1.z,
               q1.z, target, lo, hi, num, den);
    pixel_eval(D7, D8, D9, D10, ymm1.w, ym1.w, yc1.w, yp1.w,
               q1.w, target, lo, hi, num, den);
}

__device__ __forceinline__ int clampy(int v) {
    return v < 0 ? 0 : (v > H_ - 1 ? H_ - 1 : v);
}

__global__ __launch_bounds__(TPB_) void eikonal_main(
        const float* __restrict__ pred, const float* __restrict__ reach,
        double2* __restrict__ partials) {
    const float target = 1.0f / sqrtf((float)(511 * 511 + 511 * 511));
    const float lo = 0.3f * target;
    const float hi = 5.0f * target;

    int t = threadIdx.x;
    int lane = t & 63;

    // XCD-bijective swizzle (2048 % 8 == 0)
    int bswz = ((blockIdx.x & 7) << 8) + (blockIdx.x >> 3);
    // wave-uniform id -> all row addressing is SALU
    int wv = __builtin_amdgcn_readfirstlane((bswz << 2) + (t >> 6)); // 0..8191
    int b  = wv >> 8;            // image
    int y0 = (wv & 255) << 1;    // even row; wave owns rows y0, y0+1

    const float* brow = pred + b * HW_;
    int x0 = lane << 3;          // 8 px per lane

    const float* rA = brow + (clampy(y0 - 2) << 9) + x0;
    const float* rB = brow + (clampy(y0 - 1) << 9) + x0;
    const float* rC = brow + ((y0    ) << 9) + x0;
    const float* rD = brow + ((y0 + 1) << 9) + x0;
    const float* rE = brow + (clampy(y0 + 2) << 9) + x0;
    const float* rF = brow + (clampy(y0 + 3) << 9) + x0;
    const float* qC = reach + b * HW_ + ((y0    ) << 9) + x0;
    const float* qD = reach + b * HW_ + ((y0 + 1) << 9) + x0;

    // ---- issue all 16 loads (r9-validated width: no spill) ----
    f32x4 pA0 = *(const f32x4*)(rA);     f32x4 pA1 = *(const f32x4*)(rA + 4);
    f32x4 pB0 = *(const f32x4*)(rB);     f32x4 pB1 = *(const f32x4*)(rB + 4);
    f32x4 pC0 = *(const f32x4*)(rC);     f32x4 pC1 = *(const f32x4*)(rC + 4);
    f32x4 pD0 = *(const f32x4*)(rD);     f32x4 pD1 = *(const f32x4*)(rD + 4);
    f32x4 pE0 = *(const f32x4*)(rE);     f32x4 pE1 = *(const f32x4*)(rE + 4);
    f32x4 pF0 = *(const f32x4*)(rF);     f32x4 pF1 = *(const f32x4*)(rF + 4);
    f32x4 qC0 = *(const f32x4*)(qC);     f32x4 qC1 = *(const f32x4*)(qC + 4);
    f32x4 qD0 = *(const f32x4*)(qD);     f32x4 qD1 = *(const f32x4*)(qD + 4);

    // Pin all 16 loads live here (r9-validated idiom, -13%).
    asm volatile("" ::
        "v"(pA0), "v"(pA1), "v"(pB0), "v"(pB1),
        "v"(pC0), "v"(pC1), "v"(pD0), "v"(pD1),
        "v"(pE0), "v"(pE1), "v"(pF0), "v"(pF1),
        "v"(qC0), "v"(qC1), "v"(qD0), "v"(qD1));
    __builtin_amdgcn_sched_barrier(0);

    // ---- shared y forward differences (5 pairs instead of 8) ----
    f32x4 dBA0 = pB0 - pA0, dBA1 = pB1 - pA1;
    f32x4 dCB0 = pC0 - pB0, dCB1 = pC1 - pB1;
    f32x4 dDC0 = pD0 - pC0, dDC1 = pD1 - pC1;
    f32x4 dED0 = pE0 - pD0, dED1 = pE1 - pD1;
    f32x4 dFE0 = pF0 - pE0, dFE1 = pF1 - pE1;

    float num = 0.0f, den = 0.0f;

    row_eval(pC0, pC1, dBA0, dBA1, dCB0, dCB1, dDC0, dDC1, dED0, dED1,
             qC0, qC1, lane, target, lo, hi, num, den);
    row_eval(pD0, pD1, dCB0, dCB1, dDC0, dDC1, dED0, dED1, dFE0, dFE1,
             qD0, qD1, lane, target, lo, hi, num, den);

    // ---- block reduction (4 waves), no fences/atomics ----
    double dn = (double)num;
    double dd = (double)den;
    #pragma unroll
    for (int off = 32; off > 0; off >>= 1) {
        dn += __shfl_down(dn, off);
        dd += __shfl_down(dd, off);
    }
    __shared__ double sn[4], sd[4];
    int wid = t >> 6;
    if (lane == 0) { sn[wid] = dn; sd[wid] = dd; }
    __syncthreads();
    if (t == 0) {
        double2 p;
        p.x = sn[0] + sn[1] + sn[2] + sn[3];
        p.y = sd[0] + sd[1] + sd[2] + sd[3];
        partials[blockIdx.x] = p;
    }
}

__global__ __launch_bounds__(256) void eikonal_finalize(
        const double2* __restrict__ partials, float* __restrict__ out) {
    int t = threadIdx.x;
    double n = 0.0, d = 0.0;
    #pragma unroll
    for (int k = 0; k < NBLK_ / 256; ++k) {
        double2 p = partials[t + (k << 8)];
        n += p.x;
        d += p.y;
    }
    #pragma unroll
    for (int off = 32; off > 0; off >>= 1) {
        n += __shfl_down(n, off);
        d += __shfl_down(d, off);
    }
    __shared__ double sn[4], sd[4];
    int wid = t >> 6;
    int lane = t & 63;
    if (lane == 0) { sn[wid] = n; sd[wid] = d; }
    __syncthreads();
    if (t == 0) {
        double num = sn[0] + sn[1] + sn[2] + sn[3];
        double den = sd[0] + sd[1] + sd[2] + sd[3];
        if (den < 1e-8) den = 1e-8;
        out[0] = (float)(num / den);
    }
}

extern "C" void kernel_launch(void* const* d_in, const int* in_sizes, int n_in,
                              void* d_out, int out_size, void* d_ws, size_t ws_size,
                              hipStream_t stream) {
    const float* pred  = (const float*)d_in[0];
    const float* reach = (const float*)d_in[1];
    float* out = (float*)d_out;
    double2* partials = (double2*)d_ws;   // 2048 * 16B = 32 KB, fully rewritten each call

    eikonal_main<<<NBLK_, TPB_, 0, stream>>>(pred, reach, partials);
    eikonal_finalize<<<1, 256, 0, stream>>>(partials, out);
}

// Round 13
// 30.775 us; speedup vs baseline: 2.3502x; 1.0311x over previous
//
#include <hip/hip_runtime.h>

#define B_  32
#define H_  512
#define W_  512
#define HW_ (H_ * W_)
#define NWAVE_ 8192            // 32 img * 256 row-pairs; 1 wave per block
#define TPB_  64

typedef float f32x4 __attribute__((ext_vector_type(4)));

__device__ __forceinline__ float rcp_fast(float x) { return __builtin_amdgcn_rcpf(x); }

// WENO3, single fast-rcp form (validated rounds 1-12, absmax 0.0)
__device__ __forceinline__ float weno_minus(float vmm, float vm, float vp) {
    float d0 = vmm - vm, d1 = vm - vp;
    float t0 = 1e-6f + d0 * d0;
    float t1 = 1e-6f + d1 * d1;
    float s0 = t0 * t0, s1 = t1 * t1;
    float s0x2 = s0 + s0;
    float p0 = 1.5f * vm - 0.5f * vmm;
    float p1 = 0.5f * (vm + vp);
    return (s1 * p0 + s0x2 * p1) * rcp_fast(s1 + s0x2);
}

__device__ __forceinline__ float weno_plus(float vmm, float vm, float vp) {
    float d0 = vp - vm, d1 = vm - vmm;
    float t0 = 1e-6f + d0 * d0;
    float t1 = 1e-6f + d1 * d1;
    float s0 = t0 * t0, s1 = t1 * t1;
    float s0x2 = s0 + s0;
    float p0 = 1.5f * vm - 0.5f * vp;
    float p1 = 0.5f * (vm + vmm);
    return (s1 * p0 + s0x2 * p1) * rcp_fast(s1 + s0x2);
}

__device__ __forceinline__ void pixel_eval(
        float vxmm, float vxm, float vxc, float vxp,
        float vymm, float vym, float vyc, float vyp,
        float rh, float target, float lo, float hi,
        float& num, float& den) {
    float ux_minus = weno_minus(vxmm, vxm, vxc);
    float ux_plus  = weno_plus(vxm, vxc, vxp);
    float gx = fmaxf(fmaxf(ux_minus, -ux_plus), 0.0f);

    float uy_minus = weno_minus(vymm, vym, vyc);
    float uy_plus  = weno_plus(vym, vyc, vyp);
    float gy = fmaxf(fmaxf(uy_minus, -uy_plus), 0.0f);

    float gmag = __builtin_amdgcn_sqrtf(gx * gx + gy * gy + 1e-8f);

    float residual = gmag - target;
    float ar = fabsf(residual);
    float per_pixel = (ar < 0.01f) ? (50.0f * residual * residual)
                                   : (ar - 0.005f);

    bool m = (rh > 0.5f) && (gmag >= lo) && (gmag <= hi);
    float sel = m ? 1.0f : 0.0f;
    num = fmaf(sel, per_pixel, num);
    den += sel;
}

// One full row (8 px/lane); y-direction differences passed in (shared
// between the two rows this wave owns).
__device__ __forceinline__ void row_eval(
        f32x4 c0, f32x4 c1,
        f32x4 ymm0, f32x4 ymm1,
        f32x4 ym0,  f32x4 ym1,
        f32x4 yc0,  f32x4 yc1,
        f32x4 yp0,  f32x4 yp1,
        f32x4 q0, f32x4 q1,
        int lane, float target, float lo, float hi,
        float& num, float& den) {
    float xm2 = __shfl_up(c1.z, 1);
    float xm1 = __shfl_up(c1.w, 1);
    float xp1 = __shfl_down(c0.x, 1);
    float xp2 = __shfl_down(c0.y, 1);
    if (lane == 0)  { xm2 = c0.x; xm1 = c0.x; }
    if (lane == 63) { xp1 = c1.w; xp2 = c1.w; }

    float D0  = xm1 - xm2;
    float D1  = c0.x - xm1;
    float D2  = c0.y - c0.x;
    float D3  = c0.z - c0.y;
    float D4  = c0.w - c0.z;
    float D5  = c1.x - c0.w;
    float D6  = c1.y - c1.x;
    float D7  = c1.z - c1.y;
    float D8  = c1.w - c1.z;
    float D9  = xp1 - c1.w;
    float D10 = xp2 - xp1;

    pixel_eval(D0, D1, D2, D3,  ymm0.x, ym0.x, yc0.x, yp0.x,
               q0.x, target, lo, hi, num, den);
    pixel_eval(D1, D2, D3, D4,  ymm0.y, ym0.y, yc0.y, yp0.y,
               q0.y, target, lo, hi, num, den);
    pixel_eval(D2, D3, D4, D5,  ymm0.z, ym0.z, yc0.z, yp0.z,
               q0.z, target, lo, hi, num, den);
    pixel_eval(D3, D4, D5, D6,  ymm0.w, ym0.w, yc0.w, yp0.w,
               q0.w, target, lo, hi, num, den);
    pixel_eval(D4, D5, D6, D7,  ymm1.x, ym1.x, yc1.x, yp1.x,
               q1.x, target, lo, hi, num, den);
    pixel_eval(D5, D6, D7, D8,  ymm1.y, ym1.y, yc1.y, yp1.y,
               q1.y, target, lo, hi, num, den);
    pixel_eval(D6, D7, D8, D9,  ymm1.z, ym1.z, yc1.z, yp1.z,
               q1.z, target, lo, hi, num, den);
    pixel_eval(D7, D8, D9, D10, ymm1.w, ym1.w, yc1.w, yp1.w,
               q1.w, target, lo, hi, num, den);
}

__device__ __forceinline__ int clampy(int v) {
    return v < 0 ? 0 : (v > H_ - 1 ? H_ - 1 : v);
}

__global__ __launch_bounds__(TPB_) void eikonal_main(
        const float* __restrict__ pred, const float* __restrict__ reach,
        float2* __restrict__ partials) {
    const float target = 1.0f / sqrtf((float)(511 * 511 + 511 * 511));
    const float lo = 0.3f * target;
    const float hi = 5.0f * target;

    int lane = threadIdx.x & 63;

    // XCD-bijective swizzle (8192 % 8 == 0): neighboring row-pairs share halo
    // rows -> same XCD L2. blockIdx is already wave-uniform (1 wave/block).
    int wv = ((blockIdx.x & 7) << 10) + (blockIdx.x >> 3);  // 0..8191
    int b  = wv >> 8;            // image
    int y0 = (wv & 255) << 1;    // even row; wave owns rows y0, y0+1

    const float* brow = pred + b * HW_;
    int x0 = lane << 3;          // 8 px per lane

    const float* rA = brow + (clampy(y0 - 2) << 9) + x0;
    const float* rB = brow + (clampy(y0 - 1) << 9) + x0;
    const float* rC = brow + ((y0    ) << 9) + x0;
    const float* rD = brow + ((y0 + 1) << 9) + x0;
    const float* rE = brow + (clampy(y0 + 2) << 9) + x0;
    const float* rF = brow + (clampy(y0 + 3) << 9) + x0;
    const float* qC = reach + b * HW_ + ((y0    ) << 9) + x0;
    const float* qD = reach + b * HW_ + ((y0 + 1) << 9) + x0;

    // ---- issue all 16 loads (r9-validated width: no spill) ----
    f32x4 pA0 = *(const f32x4*)(rA);     f32x4 pA1 = *(const f32x4*)(rA + 4);
    f32x4 pB0 = *(const f32x4*)(rB);     f32x4 pB1 = *(const f32x4*)(rB + 4);
    f32x4 pC0 = *(const f32x4*)(rC);     f32x4 pC1 = *(const f32x4*)(rC + 4);
    f32x4 pD0 = *(const f32x4*)(rD);     f32x4 pD1 = *(const f32x4*)(rD + 4);
    f32x4 pE0 = *(const f32x4*)(rE);     f32x4 pE1 = *(const f32x4*)(rE + 4);
    f32x4 pF0 = *(const f32x4*)(rF);     f32x4 pF1 = *(const f32x4*)(rF + 4);
    f32x4 qC0 = *(const f32x4*)(qC);     f32x4 qC1 = *(const f32x4*)(qC + 4);
    f32x4 qD0 = *(const f32x4*)(qD);     f32x4 qD1 = *(const f32x4*)(qD + 4);

    // Pin all 16 loads live here (r9-validated idiom, -13%): regalloc cannot
    // sink loads to uses; all issued before one wait point.
    asm volatile("" ::
        "v"(pA0), "v"(pA1), "v"(pB0), "v"(pB1),
        "v"(pC0), "v"(pC1), "v"(pD0), "v"(pD1),
        "v"(pE0), "v"(pE1), "v"(pF0), "v"(pF1),
        "v"(qC0), "v"(qC1), "v"(qD0), "v"(qD1));
    __builtin_amdgcn_sched_barrier(0);

    // ---- shared y forward differences (5 pairs instead of 8) ----
    f32x4 dBA0 = pB0 - pA0, dBA1 = pB1 - pA1;
    f32x4 dCB0 = pC0 - pB0, dCB1 = pC1 - pB1;
    f32x4 dDC0 = pD0 - pC0, dDC1 = pD1 - pC1;
    f32x4 dED0 = pE0 - pD0, dED1 = pE1 - pD1;
    f32x4 dFE0 = pF0 - pE0, dFE1 = pF1 - pE1;

    float num = 0.0f, den = 0.0f;

    row_eval(pC0, pC1, dBA0, dBA1, dCB0, dCB1, dDC0, dDC1, dED0, dED1,
             qC0, qC1, lane, target, lo, hi, num, den);
    row_eval(pD0, pD1, dCB0, dCB1, dDC0, dDC1, dED0, dED1, dFE0, dFE1,
             qD0, qD1, lane, target, lo, hi, num, den);

    // ---- wave reduce in f32 (den exact: count <= 1024 < 2^24; num rel-err
    // ~1e-4 << 2% threshold), xor-butterfly, no LDS / no syncthreads ----
    #pragma unroll
    for (int off = 32; off > 0; off >>= 1) {
        num += __shfl_xor(num, off);
        den += __shfl_xor(den, off);
    }
    if (lane == 0) {
        partials[wv] = make_float2(num, den);
    }
}

__global__ __launch_bounds__(512) void eikonal_finalize(
        const float2* __restrict__ partials, float* __restrict__ out) {
    int t = threadIdx.x;
    double n = 0.0, d = 0.0;
    #pragma unroll
    for (int k = 0; k < NWAVE_ / 512; ++k) {
        float2 p = partials[t + (k << 9)];
        n += (double)p.x;
        d += (double)p.y;
    }
    #pragma unroll
    for (int off = 32; off > 0; off >>= 1) {
        n += __shfl_down(n, off);
        d += __shfl_down(d, off);
    }
    __shared__ double sn[8], sd[8];
    int wid = t >> 6;
    int lane = t & 63;
    if (lane == 0) { sn[wid] = n; sd[wid] = d; }
    __syncthreads();
    if (t == 0) {
        double fn = 0.0, fd = 0.0;
        #pragma unroll
        for (int k = 0; k < 8; ++k) { fn += sn[k]; fd += sd[k]; }
        if (fd < 1e-8) fd = 1e-8;
        out[0] = (float)(fn / fd);
    }
}

extern "C" void kernel_launch(void* const* d_in, const int* in_sizes, int n_in,
                              void* d_out, int out_size, void* d_ws, size_t ws_size,
                              hipStream_t stream) {
    const float* pred  = (const float*)d_in[0];
    const float* reach = (const float*)d_in[1];
    float* out = (float*)d_out;
    float2* partials = (float2*)d_ws;   // 8192 * 8B = 64 KB, fully rewritten each call

    eikonal_main<<<NWAVE_, TPB_, 0, stream>>>(pred, reach, partials);
    eikonal_finalize<<<1, 512, 0, stream>>>(partials, out);
}

// Round 14
// 26.916 us; speedup vs baseline: 2.6871x; 1.1434x over previous
//
#include <hip/hip_runtime.h>

#define B_  32
#define H_  512
#define W_  512
#define HW_ (H_ * W_)
#define NWAVE_ 8192            // 32 img * 256 row-pairs; 1 wave per block
#define TPB_  64

typedef float f32x4 __attribute__((ext_vector_type(4)));

__device__ __forceinline__ float rcp_fast(float x) { return __builtin_amdgcn_rcpf(x); }

__device__ __forceinline__ f32x4 rcp4(f32x4 v) {
    f32x4 r;
    r.x = rcp_fast(v.x); r.y = rcp_fast(v.y);
    r.z = rcp_fast(v.z); r.w = rcp_fast(v.w);
    return r;
}

// s = (1e-6 + sd^2)^2   (sign of sd irrelevant -> shared between minus/plus)
__device__ __forceinline__ f32x4 sq4(f32x4 sd) {
    f32x4 t = sd * sd + 1e-6f;
    return t * t;
}

// Generic WENO3 reconstruct with precomputed smoothness weights.
// minus(D[i],D[i+1],D[i+2])  == core(s[i],   s[i+1], D[i+1], D[i],   D[i+2])
// plus (D[i+1],D[i+2],D[i+3])== core(s[i+2], s[i+1], D[i+2], D[i+3], D[i+1])
__device__ __forceinline__ float core(float sOut, float sMid,
                                      float fMain, float fOut, float fPair) {
    float p0 = 1.5f * fMain - 0.5f * fOut;
    float p1 = 0.5f * (fMain + fPair);
    float s2 = sOut + sOut;
    return (sMid * p0 + s2 * p1) * rcp_fast(sMid + s2);
}

__device__ __forceinline__ f32x4 coreV(f32x4 sOut, f32x4 sMid,
                                       f32x4 fMain, f32x4 fOut, f32x4 fPair) {
    f32x4 p0 = 1.5f * fMain - 0.5f * fOut;
    f32x4 p1 = 0.5f * (fMain + fPair);
    f32x4 s2 = sOut + sOut;
    return (sMid * p0 + s2 * p1) * rcp4(sMid + s2);
}

// gy = relu-max combine of minus/plus
__device__ __forceinline__ f32x4 gyV(f32x4 um, f32x4 up) {
    f32x4 g;
    g.x = fmaxf(fmaxf(um.x, -up.x), 0.0f);
    g.y = fmaxf(fmaxf(um.y, -up.y), 0.0f);
    g.z = fmaxf(fmaxf(um.z, -up.z), 0.0f);
    g.w = fmaxf(fmaxf(um.w, -up.w), 0.0f);
    return g;
}

// One full row (8 px/lane): x-direction WENO with sliding shared smoothness,
// y-direction gy passed in precomputed.
__device__ __forceinline__ void row_process(
        f32x4 c0, f32x4 c1,
        f32x4 gy0, f32x4 gy1,
        f32x4 q0, f32x4 q1,
        int lane, float target, float lo, float hi,
        float& num, float& den) {
    float xm2 = __shfl_up(c1.z, 1);
    float xm1 = __shfl_up(c1.w, 1);
    float xp1 = __shfl_down(c0.x, 1);
    float xp2 = __shfl_down(c0.y, 1);
    if (lane == 0)  { xm2 = c0.x; xm1 = c0.x; }
    if (lane == 63) { xp1 = c1.w; xp2 = c1.w; }

    // w[0..11] = u at x0-2 .. x0+9 ; D[k] = w[k+1]-w[k]
    float D[11];
    D[0]  = xm1  - xm2;
    D[1]  = c0.x - xm1;
    D[2]  = c0.y - c0.x;
    D[3]  = c0.z - c0.y;
    D[4]  = c0.w - c0.z;
    D[5]  = c1.x - c0.w;
    D[6]  = c1.y - c1.x;
    D[7]  = c1.z - c1.y;
    D[8]  = c1.w - c1.z;
    D[9]  = xp1  - c1.w;
    D[10] = xp2  - xp1;

    // shared smoothness: s[k] = (1e-6 + (D[k]-D[k+1])^2)^2, k=0..9
    float s[10];
    #pragma unroll
    for (int k = 0; k < 10; ++k) {
        float sd = D[k] - D[k + 1];
        float t = fmaf(sd, sd, 1e-6f);
        s[k] = t * t;
    }

    #pragma unroll
    for (int i = 0; i < 8; ++i) {
        float um = core(s[i],     s[i + 1], D[i + 1], D[i],     D[i + 2]);
        float up = core(s[i + 2], s[i + 1], D[i + 2], D[i + 3], D[i + 1]);
        float gx = fmaxf(fmaxf(um, -up), 0.0f);
        float gy = (i < 4) ? gy0[i] : gy1[i - 4];
        float q  = (i < 4) ? q0[i]  : q1[i - 4];

        float gmag = __builtin_amdgcn_sqrtf(fmaf(gx, gx, fmaf(gy, gy, 1e-8f)));
        float r  = gmag - target;
        float ar = fabsf(r);
        float pp = (ar < 0.01f) ? (50.0f * r * r) : (ar - 0.005f);
        bool  m  = (q > 0.5f) && (gmag >= lo) && (gmag <= hi);
        float sel = m ? 1.0f : 0.0f;
        num = fmaf(sel, pp, num);
        den += sel;
    }
}

__device__ __forceinline__ int clampy(int v) {
    return v < 0 ? 0 : (v > H_ - 1 ? H_ - 1 : v);
}

__global__ __launch_bounds__(TPB_) void eikonal_main(
        const float* __restrict__ pred, const float* __restrict__ reach,
        float2* __restrict__ partials) {
    const float target = 1.0f / sqrtf((float)(511 * 511 + 511 * 511));
    const float lo = 0.3f * target;
    const float hi = 5.0f * target;

    int lane = threadIdx.x & 63;

    // XCD-bijective swizzle (8192 % 8 == 0)
    int wv = ((blockIdx.x & 7) << 10) + (blockIdx.x >> 3);  // 0..8191
    int b  = wv >> 8;            // image
    int y0 = (wv & 255) << 1;    // even row; wave owns rows y0, y0+1

    const float* brow = pred + b * HW_;
    int x0 = lane << 3;          // 8 px per lane

    const float* rA = brow + (clampy(y0 - 2) << 9) + x0;
    const float* rB = brow + (clampy(y0 - 1) << 9) + x0;
    const float* rC = brow + ((y0    ) << 9) + x0;
    const float* rD = brow + ((y0 + 1) << 9) + x0;
    const float* rE = brow + (clampy(y0 + 2) << 9) + x0;
    const float* rF = brow + (clampy(y0 + 3) << 9) + x0;
    const float* qCp = reach + b * HW_ + ((y0    ) << 9) + x0;
    const float* qDp = reach + b * HW_ + ((y0 + 1) << 9) + x0;

    // ---- issue all 16 loads (r9-validated width: no spill) ----
    f32x4 pA0 = *(const f32x4*)(rA);     f32x4 pA1 = *(const f32x4*)(rA + 4);
    f32x4 pB0 = *(const f32x4*)(rB);     f32x4 pB1 = *(const f32x4*)(rB + 4);
    f32x4 pC0 = *(const f32x4*)(rC);     f32x4 pC1 = *(const f32x4*)(rC + 4);
    f32x4 pD0 = *(const f32x4*)(rD);     f32x4 pD1 = *(const f32x4*)(rD + 4);
    f32x4 pE0 = *(const f32x4*)(rE);     f32x4 pE1 = *(const f32x4*)(rE + 4);
    f32x4 pF0 = *(const f32x4*)(rF);     f32x4 pF1 = *(const f32x4*)(rF + 4);
    f32x4 qC0 = *(const f32x4*)(qCp);    f32x4 qC1 = *(const f32x4*)(qCp + 4);
    f32x4 qD0 = *(const f32x4*)(qDp);    f32x4 qD1 = *(const f32x4*)(qDp + 4);

    // Pin all 16 loads live (r9-validated idiom, -13%)
    asm volatile("" ::
        "v"(pA0), "v"(pA1), "v"(pB0), "v"(pB1),
        "v"(pC0), "v"(pC1), "v"(pD0), "v"(pD1),
        "v"(pE0), "v"(pE1), "v"(pF0), "v"(pF1),
        "v"(qC0), "v"(qC1), "v"(qD0), "v"(qD1));
    __builtin_amdgcn_sched_barrier(0);

    // ---- y first differences (5 unique, shared by both rows) ----
    f32x4 dBA0 = pB0 - pA0, dBA1 = pB1 - pA1;
    f32x4 dCB0 = pC0 - pB0, dCB1 = pC1 - pB1;
    f32x4 dDC0 = pD0 - pC0, dDC1 = pD1 - pC1;
    f32x4 dED0 = pE0 - pD0, dED1 = pE1 - pD1;
    f32x4 dFE0 = pF0 - pE0, dFE1 = pF1 - pE1;

    // ---- y shared smoothness (4 unique levels serve 8 weno calls) ----
    f32x4 sy0_0 = sq4(dBA0 - dCB0), sy0_1 = sq4(dBA1 - dCB1);
    f32x4 sy1_0 = sq4(dCB0 - dDC0), sy1_1 = sq4(dCB1 - dDC1);
    f32x4 sy2_0 = sq4(dDC0 - dED0), sy2_1 = sq4(dDC1 - dED1);
    f32x4 sy3_0 = sq4(dED0 - dFE0), sy3_1 = sq4(dED1 - dFE1);

    // ---- y-direction gy for both rows (vector element-wise WENO) ----
    // row C: minus(dBA,dCB,dDC) / plus(dCB,dDC,dED)
    f32x4 gyC0 = gyV(coreV(sy0_0, sy1_0, dCB0, dBA0, dDC0),
                     coreV(sy2_0, sy1_0, dDC0, dED0, dCB0));
    f32x4 gyC1 = gyV(coreV(sy0_1, sy1_1, dCB1, dBA1, dDC1),
                     coreV(sy2_1, sy1_1, dDC1, dED1, dCB1));
    // row D: minus(dCB,dDC,dED) / plus(dDC,dED,dFE)
    f32x4 gyD0 = gyV(coreV(sy1_0, sy2_0, dDC0, dCB0, dED0),
                     coreV(sy3_0, sy2_0, dED0, dFE0, dDC0));
    f32x4 gyD1 = gyV(coreV(sy1_1, sy2_1, dDC1, dCB1, dED1),
                     coreV(sy3_1, sy2_1, dED1, dFE1, dDC1));

    float num = 0.0f, den = 0.0f;

    row_process(pC0, pC1, gyC0, gyC1, qC0, qC1, lane, target, lo, hi, num, den);
    row_process(pD0, pD1, gyD0, gyD1, qD0, qD1, lane, target, lo, hi, num, den);

    // ---- wave reduce in f32 (den exact <= 1024; num rel-err ~1e-4 << 2%) ----
    #pragma unroll
    for (int off = 32; off > 0; off >>= 1) {
        num += __shfl_xor(num, off);
        den += __shfl_xor(den, off);
    }
    if (lane == 0) {
        partials[wv] = make_float2(num, den);
    }
}

__global__ __launch_bounds__(512) void eikonal_finalize(
        const float2* __restrict__ partials, float* __restrict__ out) {
    int t = threadIdx.x;
    double n = 0.0, d = 0.0;
    #pragma unroll
    for (int k = 0; k < NWAVE_ / 512; ++k) {
        float2 p = partials[t + (k << 9)];
        n += (double)p.x;
        d += (double)p.y;
    }
    #pragma unroll
    for (int off = 32; off > 0; off >>= 1) {
        n += __shfl_down(n, off);
        d += __shfl_down(d, off);
    }
    __shared__ double sn[8], sd[8];
    int wid = t >> 6;
    int lane = t & 63;
    if (lane == 0) { sn[wid] = n; sd[wid] = d; }
    __syncthreads();
    if (t == 0) {
        double fn = 0.0, fd = 0.0;
        #pragma unroll
        for (int k = 0; k < 8; ++k) { fn += sn[k]; fd += sd[k]; }
        if (fd < 1e-8) fd = 1e-8;
        out[0] = (float)(fn / fd);
    }
}

extern "C" void kernel_launch(void* const* d_in, const int* in_sizes, int n_in,
                              void* d_out, int out_size, void* d_ws, size_t ws_size,
                              hipStream_t stream) {
    const float* pred  = (const float*)d_in[0];
    const float* reach = (const float*)d_in[1];
    float* out = (float*)d_out;
    float2* partials = (float2*)d_ws;   // 8192 * 8B = 64 KB, fully rewritten each call

    eikonal_main<<<NWAVE_, TPB_, 0, stream>>>(pred, reach, partials);
    eikonal_finalize<<<1, 512, 0, stream>>>(partials, out);
}

// Round 15
// 25.009 us; speedup vs baseline: 2.8920x; 1.0763x over previous
//
#include <hip/hip_runtime.h>

#define B_  32
#define H_  512
#define W_  512
#define HW_ (H_ * W_)
#define NWAVE_ 8192            // 32 img * 256 row-pairs
#define NBLK_ 4096             // 2 waves per block
#define TPB_  128

typedef float f32x4 __attribute__((ext_vector_type(4)));

__device__ __forceinline__ float rcp_fast(float x) { return __builtin_amdgcn_rcpf(x); }

__device__ __forceinline__ f32x4 rcp4(f32x4 v) {
    f32x4 r;
    r.x = rcp_fast(v.x); r.y = rcp_fast(v.y);
    r.z = rcp_fast(v.z); r.w = rcp_fast(v.w);
    return r;
}

// s = (1e-6 + sd^2)^2  (sign-free -> shared between minus/plus stencils)
__device__ __forceinline__ f32x4 sq4(f32x4 sd) {
    f32x4 t = sd * sd + 1e-6f;
    return t * t;
}

// WENO3 reconstruct, w-form: result = w*(p0-p1) + p1, w = sMid/(sMid+2sOut).
// Algebraically == (sMid*p0 + 2sOut*p1)/(sMid+2sOut); 7 VALU + 1 rcp.
__device__ __forceinline__ float core(float sOut, float sMid,
                                      float fMain, float fOut, float fPair) {
    float a    = fMain + fPair;                 // 2*p1
    float b    = fOut + fPair;
    float diff = fmaf(-0.5f, b, fMain);         // p0 - p1
    float den  = fmaf(2.0f, sOut, sMid);
    float w    = sMid * rcp_fast(den);
    return fmaf(w, diff, 0.5f * a);
}

__device__ __forceinline__ f32x4 coreV(f32x4 sOut, f32x4 sMid,
                                       f32x4 fMain, f32x4 fOut, f32x4 fPair) {
    f32x4 a    = fMain + fPair;
    f32x4 b    = fOut + fPair;
    f32x4 diff = fMain - 0.5f * b;
    f32x4 den  = sMid + 2.0f * sOut;
    f32x4 w    = sMid * rcp4(den);
    return w * diff + 0.5f * a;
}

__device__ __forceinline__ f32x4 gyV(f32x4 um, f32x4 up) {
    f32x4 g;
    g.x = fmaxf(fmaxf(um.x, -up.x), 0.0f);
    g.y = fmaxf(fmaxf(um.y, -up.y), 0.0f);
    g.z = fmaxf(fmaxf(um.z, -up.z), 0.0f);
    g.w = fmaxf(fmaxf(um.w, -up.w), 0.0f);
    return g;
}

// One full row (8 px/lane): x-direction WENO with sliding shared smoothness;
// y-direction gy precomputed.
__device__ __forceinline__ void row_process(
        f32x4 c0, f32x4 c1,
        f32x4 gy0, f32x4 gy1,
        f32x4 q0, f32x4 q1,
        int lane, float target, float lo, float hi,
        float& num, float& den) {
    float xm2 = __shfl_up(c1.z, 1);
    float xm1 = __shfl_up(c1.w, 1);
    float xp1 = __shfl_down(c0.x, 1);
    float xp2 = __shfl_down(c0.y, 1);
    if (lane == 0)  { xm2 = c0.x; xm1 = c0.x; }
    if (lane == 63) { xp1 = c1.w; xp2 = c1.w; }

    // w[0..11] = u at x0-2 .. x0+9 ; D[k] = w[k+1]-w[k]
    float D[11];
    D[0]  = xm1  - xm2;
    D[1]  = c0.x - xm1;
    D[2]  = c0.y - c0.x;
    D[3]  = c0.z - c0.y;
    D[4]  = c0.w - c0.z;
    D[5]  = c1.x - c0.w;
    D[6]  = c1.y - c1.x;
    D[7]  = c1.z - c1.y;
    D[8]  = c1.w - c1.z;
    D[9]  = xp1  - c1.w;
    D[10] = xp2  - xp1;

    // shared smoothness: s[k] = (1e-6 + (D[k]-D[k+1])^2)^2
    float s[10];
    #pragma unroll
    for (int k = 0; k < 10; ++k) {
        float sd = D[k] - D[k + 1];
        float t = fmaf(sd, sd, 1e-6f);
        s[k] = t * t;
    }

    #pragma unroll
    for (int i = 0; i < 8; ++i) {
        float um = core(s[i],     s[i + 1], D[i + 1], D[i],     D[i + 2]);
        float up = core(s[i + 2], s[i + 1], D[i + 2], D[i + 3], D[i + 1]);
        float gx = fmaxf(fmaxf(um, -up), 0.0f);
        float gy = (i < 4) ? gy0[i] : gy1[i - 4];
        float q  = (i < 4) ? q0[i]  : q1[i - 4];

        float gmag = __builtin_amdgcn_sqrtf(fmaf(gx, gx, fmaf(gy, gy, 1e-8f)));
        float r  = gmag - target;
        float ar = fabsf(r);
        float pp = (ar < 0.01f) ? (50.0f * r * r) : (ar - 0.005f);
        bool  m  = (q > 0.5f) && (gmag >= lo) && (gmag <= hi);
        float sel = m ? 1.0f : 0.0f;
        num = fmaf(sel, pp, num);
        den += sel;
    }
}

__device__ __forceinline__ int clampy(int v) {
    return v < 0 ? 0 : (v > H_ - 1 ? H_ - 1 : v);
}

__global__ __launch_bounds__(TPB_) void eikonal_main(
        const float* __restrict__ pred, const float* __restrict__ reach,
        float2* __restrict__ partials) {
    const float target = 1.0f / sqrtf((float)(511 * 511 + 511 * 511));
    const float lo = 0.3f * target;
    const float hi = 5.0f * target;

    int t = threadIdx.x;
    int lane = t & 63;

    // XCD-bijective swizzle (4096 % 8 == 0); 2 waves/block -> better CU
    // workgroup-slot utilization than 1-wave blocks.
    int bswz = ((blockIdx.x & 7) << 9) + (blockIdx.x >> 3);
    int wv = __builtin_amdgcn_readfirstlane((bswz << 1) + (t >> 6)); // 0..8191
    int b  = wv >> 8;            // image
    int y0 = (wv & 255) << 1;    // even row; wave owns rows y0, y0+1

    const float* brow = pred + b * HW_;
    int x0 = lane << 3;          // 8 px per lane

    const float* rA = brow + (clampy(y0 - 2) << 9) + x0;
    const float* rB = brow + (clampy(y0 - 1) << 9) + x0;
    const float* rC = brow + ((y0    ) << 9) + x0;
    const float* rD = brow + ((y0 + 1) << 9) + x0;
    const float* rE = brow + (clampy(y0 + 2) << 9) + x0;
    const float* rF = brow + (clampy(y0 + 3) << 9) + x0;
    const f32x4* qCp = (const f32x4*)(reach + b * HW_ + ((y0    ) << 9) + x0);
    const f32x4* qDp = (const f32x4*)(reach + b * HW_ + ((y0 + 1) << 9) + x0);

    // ---- issue all 16 loads; reach is streaming-only -> non-temporal ----
    f32x4 pA0 = *(const f32x4*)(rA);     f32x4 pA1 = *(const f32x4*)(rA + 4);
    f32x4 pB0 = *(const f32x4*)(rB);     f32x4 pB1 = *(const f32x4*)(rB + 4);
    f32x4 pC0 = *(const f32x4*)(rC);     f32x4 pC1 = *(const f32x4*)(rC + 4);
    f32x4 pD0 = *(const f32x4*)(rD);     f32x4 pD1 = *(const f32x4*)(rD + 4);
    f32x4 pE0 = *(const f32x4*)(rE);     f32x4 pE1 = *(const f32x4*)(rE + 4);
    f32x4 pF0 = *(const f32x4*)(rF);     f32x4 pF1 = *(const f32x4*)(rF + 4);
    f32x4 qC0 = __builtin_nontemporal_load(qCp);
    f32x4 qC1 = __builtin_nontemporal_load(qCp + 1);
    f32x4 qD0 = __builtin_nontemporal_load(qDp);
    f32x4 qD1 = __builtin_nontemporal_load(qDp + 1);

    // Pin all 16 loads live (r9-validated idiom, -13%)
    asm volatile("" ::
        "v"(pA0), "v"(pA1), "v"(pB0), "v"(pB1),
        "v"(pC0), "v"(pC1), "v"(pD0), "v"(pD1),
        "v"(pE0), "v"(pE1), "v"(pF0), "v"(pF1),
        "v"(qC0), "v"(qC1), "v"(qD0), "v"(qD1));
    __builtin_amdgcn_sched_barrier(0);

    // ---- y first differences (5 unique, shared by both rows) ----
    f32x4 dBA0 = pB0 - pA0, dBA1 = pB1 - pA1;
    f32x4 dCB0 = pC0 - pB0, dCB1 = pC1 - pB1;
    f32x4 dDC0 = pD0 - pC0, dDC1 = pD1 - pC1;
    f32x4 dED0 = pE0 - pD0, dED1 = pE1 - pD1;
    f32x4 dFE0 = pF0 - pE0, dFE1 = pF1 - pE1;

    // ---- y shared smoothness (4 unique levels serve 8 weno calls) ----
    f32x4 sy0_0 = sq4(dBA0 - dCB0), sy0_1 = sq4(dBA1 - dCB1);
    f32x4 sy1_0 = sq4(dCB0 - dDC0), sy1_1 = sq4(dCB1 - dDC1);
    f32x4 sy2_0 = sq4(dDC0 - dED0), sy2_1 = sq4(dDC1 - dED1);
    f32x4 sy3_0 = sq4(dED0 - dFE0), sy3_1 = sq4(dED1 - dFE1);

    // ---- y-direction gy for both rows ----
    f32x4 gyC0 = gyV(coreV(sy0_0, sy1_0, dCB0, dBA0, dDC0),
                     coreV(sy2_0, sy1_0, dDC0, dED0, dCB0));
    f32x4 gyC1 = gyV(coreV(sy0_1, sy1_1, dCB1, dBA1, dDC1),
                     coreV(sy2_1, sy1_1, dDC1, dED1, dCB1));
    f32x4 gyD0 = gyV(coreV(sy1_0, sy2_0, dDC0, dCB0, dED0),
                     coreV(sy3_0, sy2_0, dED0, dFE0, dDC0));
    f32x4 gyD1 = gyV(coreV(sy1_1, sy2_1, dDC1, dCB1, dED1),
                     coreV(sy3_1, sy2_1, dED1, dFE1, dDC1));

    float num = 0.0f, den = 0.0f;

    row_process(pC0, pC1, gyC0, gyC1, qC0, qC1, lane, target, lo, hi, num, den);
    row_process(pD0, pD1, gyD0, gyD1, qD0, qD1, lane, target, lo, hi, num, den);

    // ---- wave reduce in f32 (den exact <= 1024; num rel-err ~1e-4 << 2%) ----
    #pragma unroll
    for (int off = 32; off > 0; off >>= 1) {
        num += __shfl_xor(num, off);
        den += __shfl_xor(den, off);
    }
    if (lane == 0) {
        partials[wv] = make_float2(num, den);
    }
}

__global__ __launch_bounds__(512) void eikonal_finalize(
        const float2* __restrict__ partials, float* __restrict__ out) {
    int t = threadIdx.x;
    double n = 0.0, d = 0.0;
    #pragma unroll
    for (int k = 0; k < NWAVE_ / 512; ++k) {
        float2 p = partials[t + (k << 9)];
        n += (double)p.x;
        d += (double)p.y;
    }
    #pragma unroll
    for (int off = 32; off > 0; off >>= 1) {
        n += __shfl_down(n, off);
        d += __shfl_down(d, off);
    }
    __shared__ double sn[8], sd[8];
    int wid = t >> 6;
    int lane = t & 63;
    if (lane == 0) { sn[wid] = n; sd[wid] = d; }
    __syncthreads();
    if (t == 0) {
        double fn = 0.0, fd = 0.0;
        #pragma unroll
        for (int k = 0; k < 8; ++k) { fn += sn[k]; fd += sd[k]; }
        if (fd < 1e-8) fd = 1e-8;
        out[0] = (float)(fn / fd);
    }
}

extern "C" void kernel_launch(void* const* d_in, const int* in_sizes, int n_in,
                              void* d_out, int out_size, void* d_ws, size_t ws_size,
                              hipStream_t stream) {
    const float* pred  = (const float*)d_in[0];
    const float* reach = (const float*)d_in[1];
    float* out = (float*)d_out;
    float2* partials = (float2*)d_ws;   // 8192 * 8B = 64 KB, fully rewritten each call

    eikonal_main<<<NBLK_, TPB_, 0, stream>>>(pred, reach, partials);
    eikonal_finalize<<<1, 512, 0, stream>>>(partials, out);
}

// Round 16
// 24.490 us; speedup vs baseline: 2.9532x; 1.0212x over previous
//
#include <hip/hip_runtime.h>

#define B_  32
#define H_  512
#define W_  512
#define HW_ (H_ * W_)
#define NWAVE_ 4096            // 32 img * 128 row-quads; 2 waves per block
#define NBLK_ 2048
#define TPB_  128

typedef float f32x4 __attribute__((ext_vector_type(4)));

__device__ __forceinline__ float rcp_fast(float x) { return __builtin_amdgcn_rcpf(x); }

__device__ __forceinline__ f32x4 rcp4(f32x4 v) {
    f32x4 r;
    r.x = rcp_fast(v.x); r.y = rcp_fast(v.y);
    r.z = rcp_fast(v.z); r.w = rcp_fast(v.w);
    return r;
}

// s = (1e-6 + sd^2)^2  (sign-free -> shared between minus/plus stencils)
__device__ __forceinline__ f32x4 sq4(f32x4 sd) {
    f32x4 t = sd * sd + 1e-6f;
    return t * t;
}

// WENO3 reconstruct, w-form: result = w*(p0-p1) + p1, w = sMid/(sMid+2sOut).
__device__ __forceinline__ float core(float sOut, float sMid,
                                      float fMain, float fOut, float fPair) {
    float a    = fMain + fPair;                 // 2*p1
    float b    = fOut + fPair;
    float diff = fmaf(-0.5f, b, fMain);         // p0 - p1
    float den  = fmaf(2.0f, sOut, sMid);
    float w    = sMid * rcp_fast(den);
    return fmaf(w, diff, 0.5f * a);
}

__device__ __forceinline__ f32x4 coreV(f32x4 sOut, f32x4 sMid,
                                       f32x4 fMain, f32x4 fOut, f32x4 fPair) {
    f32x4 a    = fMain + fPair;
    f32x4 b    = fOut + fPair;
    f32x4 diff = fMain - 0.5f * b;
    f32x4 den  = sMid + 2.0f * sOut;
    f32x4 w    = sMid * rcp4(den);
    return w * diff + 0.5f * a;
}

__device__ __forceinline__ f32x4 gyV(f32x4 um, f32x4 up) {
    f32x4 g;
    g.x = fmaxf(fmaxf(um.x, -up.x), 0.0f);
    g.y = fmaxf(fmaxf(um.y, -up.y), 0.0f);
    g.z = fmaxf(fmaxf(um.z, -up.z), 0.0f);
    g.w = fmaxf(fmaxf(um.w, -up.w), 0.0f);
    return g;
}

// One full row (8 px/lane): x-direction WENO with sliding shared smoothness;
// y-direction gy precomputed.
__device__ __forceinline__ void row_process(
        f32x4 c0, f32x4 c1,
        f32x4 gy0, f32x4 gy1,
        f32x4 q0, f32x4 q1,
        int lane, float target, float lo, float hi,
        float& num, float& den) {
    float xm2 = __shfl_up(c1.z, 1);
    float xm1 = __shfl_up(c1.w, 1);
    float xp1 = __shfl_down(c0.x, 1);
    float xp2 = __shfl_down(c0.y, 1);
    if (lane == 0)  { xm2 = c0.x; xm1 = c0.x; }
    if (lane == 63) { xp1 = c1.w; xp2 = c1.w; }

    float D[11];
    D[0]  = xm1  - xm2;
    D[1]  = c0.x - xm1;
    D[2]  = c0.y - c0.x;
    D[3]  = c0.z - c0.y;
    D[4]  = c0.w - c0.z;
    D[5]  = c1.x - c0.w;
    D[6]  = c1.y - c1.x;
    D[7]  = c1.z - c1.y;
    D[8]  = c1.w - c1.z;
    D[9]  = xp1  - c1.w;
    D[10] = xp2  - xp1;

    float s[10];
    #pragma unroll
    for (int k = 0; k < 10; ++k) {
        float sd = D[k] - D[k + 1];
        float t = fmaf(sd, sd, 1e-6f);
        s[k] = t * t;
    }

    #pragma unroll
    for (int i = 0; i < 8; ++i) {
        float um = core(s[i],     s[i + 1], D[i + 1], D[i],     D[i + 2]);
        float up = core(s[i + 2], s[i + 1], D[i + 2], D[i + 3], D[i + 1]);
        float gx = fmaxf(fmaxf(um, -up), 0.0f);
        float gy = (i < 4) ? gy0[i] : gy1[i - 4];
        float q  = (i < 4) ? q0[i]  : q1[i - 4];

        float gmag = __builtin_amdgcn_sqrtf(fmaf(gx, gx, fmaf(gy, gy, 1e-8f)));
        float r  = gmag - target;
        float ar = fabsf(r);
        float pp = (ar < 0.01f) ? (50.0f * r * r) : (ar - 0.005f);
        bool  m  = (q > 0.5f) && (gmag >= lo) && (gmag <= hi);
        float sel = m ? 1.0f : 0.0f;
        num = fmaf(sel, pp, num);
        den += sel;
    }
}

__device__ __forceinline__ int clampy(int v) {
    return v < 0 ? 0 : (v > H_ - 1 ? H_ - 1 : v);
}

__global__ __launch_bounds__(TPB_) void eikonal_main(
        const float* __restrict__ pred, const float* __restrict__ reach,
        float2* __restrict__ partials) {
    const float target = 1.0f / sqrtf((float)(511 * 511 + 511 * 511));
    const float lo = 0.3f * target;
    const float hi = 5.0f * target;

    int t = threadIdx.x;
    int lane = t & 63;

    // XCD-bijective swizzle (2048 % 8 == 0); 2 waves/block
    int bswz = ((blockIdx.x & 7) << 8) + (blockIdx.x >> 3);
    int wv = __builtin_amdgcn_readfirstlane((bswz << 1) + (t >> 6)); // 0..4095
    int b  = wv >> 7;            // image
    int y0 = (wv & 127) << 2;    // wave owns rows y0..y0+3

    const float* brow = pred + b * HW_;
    const float* rrow = reach + b * HW_;
    int x0 = lane << 3;          // 8 px per lane

    const float* rA = brow + (clampy(y0 - 2) << 9) + x0;
    const float* rB = brow + (clampy(y0 - 1) << 9) + x0;
    const float* rC = brow + ((y0    ) << 9) + x0;
    const float* rD = brow + ((y0 + 1) << 9) + x0;
    const float* rE = brow + ((y0 + 2) << 9) + x0;
    const float* rF = brow + ((y0 + 3) << 9) + x0;
    const float* rG = brow + (clampy(y0 + 4) << 9) + x0;
    const float* rH = brow + (clampy(y0 + 5) << 9) + x0;
    const f32x4* qCp = (const f32x4*)(rrow + ((y0    ) << 9) + x0);
    const f32x4* qDp = (const f32x4*)(rrow + ((y0 + 1) << 9) + x0);
    const f32x4* qEp = (const f32x4*)(rrow + ((y0 + 2) << 9) + x0);
    const f32x4* qFp = (const f32x4*)(rrow + ((y0 + 3) << 9) + x0);

    // ---- issue all 24 loads; reach streaming -> non-temporal ----
    f32x4 pA0 = *(const f32x4*)(rA);  f32x4 pA1 = *(const f32x4*)(rA + 4);
    f32x4 pB0 = *(const f32x4*)(rB);  f32x4 pB1 = *(const f32x4*)(rB + 4);
    f32x4 pC0 = *(const f32x4*)(rC);  f32x4 pC1 = *(const f32x4*)(rC + 4);
    f32x4 pD0 = *(const f32x4*)(rD);  f32x4 pD1 = *(const f32x4*)(rD + 4);
    f32x4 pE0 = *(const f32x4*)(rE);  f32x4 pE1 = *(const f32x4*)(rE + 4);
    f32x4 pF0 = *(const f32x4*)(rF);  f32x4 pF1 = *(const f32x4*)(rF + 4);
    f32x4 pG0 = *(const f32x4*)(rG);  f32x4 pG1 = *(const f32x4*)(rG + 4);
    f32x4 pH0 = *(const f32x4*)(rH);  f32x4 pH1 = *(const f32x4*)(rH + 4);
    f32x4 qC0 = __builtin_nontemporal_load(qCp);
    f32x4 qC1 = __builtin_nontemporal_load(qCp + 1);
    f32x4 qD0 = __builtin_nontemporal_load(qDp);
    f32x4 qD1 = __builtin_nontemporal_load(qDp + 1);
    f32x4 qE0 = __builtin_nontemporal_load(qEp);
    f32x4 qE1 = __builtin_nontemporal_load(qEp + 1);
    f32x4 qF0 = __builtin_nontemporal_load(qFp);
    f32x4 qF1 = __builtin_nontemporal_load(qFp + 1);

    // Pin all 24 loads live. NO launch-bounds cap this time: r10's spill came
    // from the (256,4)=128-VGPR cap, not the pin width. Allocator is free to
    // take ~150 VGPR.
    asm volatile("" ::
        "v"(pA0), "v"(pA1), "v"(pB0), "v"(pB1),
        "v"(pC0), "v"(pC1), "v"(pD0), "v"(pD1),
        "v"(pE0), "v"(pE1), "v"(pF0), "v"(pF1),
        "v"(pG0), "v"(pG1), "v"(pH0), "v"(pH1),
        "v"(qC0), "v"(qC1), "v"(qD0), "v"(qD1),
        "v"(qE0), "v"(qE1), "v"(qF0), "v"(qF1));
    __builtin_amdgcn_sched_barrier(0);

    // ---- y first differences (7 unique, serve 4 rows) ----
    f32x4 dBA0 = pB0 - pA0, dBA1 = pB1 - pA1;
    f32x4 dCB0 = pC0 - pB0, dCB1 = pC1 - pB1;
    f32x4 dDC0 = pD0 - pC0, dDC1 = pD1 - pC1;
    f32x4 dED0 = pE0 - pD0, dED1 = pE1 - pD1;
    f32x4 dFE0 = pF0 - pE0, dFE1 = pF1 - pE1;
    f32x4 dGF0 = pG0 - pF0, dGF1 = pG1 - pF1;
    f32x4 dHG0 = pH0 - pG0, dHG1 = pH1 - pG1;

    // ---- y shared smoothness (6 unique levels serve 16 weno calls) ----
    f32x4 s0_0 = sq4(dBA0 - dCB0), s0_1 = sq4(dBA1 - dCB1);
    f32x4 s1_0 = sq4(dCB0 - dDC0), s1_1 = sq4(dCB1 - dDC1);
    f32x4 s2_0 = sq4(dDC0 - dED0), s2_1 = sq4(dDC1 - dED1);
    f32x4 s3_0 = sq4(dED0 - dFE0), s3_1 = sq4(dED1 - dFE1);
    f32x4 s4_0 = sq4(dFE0 - dGF0), s4_1 = sq4(dFE1 - dGF1);
    f32x4 s5_0 = sq4(dGF0 - dHG0), s5_1 = sq4(dGF1 - dHG1);

    // ---- y-direction gy for the 4 rows ----
    f32x4 gyC0 = gyV(coreV(s0_0, s1_0, dCB0, dBA0, dDC0),
                     coreV(s2_0, s1_0, dDC0, dED0, dCB0));
    f32x4 gyC1 = gyV(coreV(s0_1, s1_1, dCB1, dBA1, dDC1),
                     coreV(s2_1, s1_1, dDC1, dED1, dCB1));
    f32x4 gyD0 = gyV(coreV(s1_0, s2_0, dDC0, dCB0, dED0),
                     coreV(s3_0, s2_0, dED0, dFE0, dDC0));
    f32x4 gyD1 = gyV(coreV(s1_1, s2_1, dDC1, dCB1, dED1),
                     coreV(s3_1, s2_1, dED1, dFE1, dDC1));
    f32x4 gyE0 = gyV(coreV(s2_0, s3_0, dED0, dDC0, dFE0),
                     coreV(s4_0, s3_0, dFE0, dGF0, dED0));
    f32x4 gyE1 = gyV(coreV(s2_1, s3_1, dED1, dDC1, dFE1),
                     coreV(s4_1, s3_1, dFE1, dGF1, dED1));
    f32x4 gyF0 = gyV(coreV(s3_0, s4_0, dFE0, dED0, dGF0),
                     coreV(s5_0, s4_0, dGF0, dHG0, dFE0));
    f32x4 gyF1 = gyV(coreV(s3_1, s4_1, dFE1, dED1, dGF1),
                     coreV(s5_1, s4_1, dGF1, dHG1, dFE1));

    float num = 0.0f, den = 0.0f;

    row_process(pC0, pC1, gyC0, gyC1, qC0, qC1, lane, target, lo, hi, num, den);
    row_process(pD0, pD1, gyD0, gyD1, qD0, qD1, lane, target, lo, hi, num, den);
    row_process(pE0, pE1, gyE0, gyE1, qE0, qE1, lane, target, lo, hi, num, den);
    row_process(pF0, pF1, gyF0, gyF1, qF0, qF1, lane, target, lo, hi, num, den);

    // ---- wave reduce in f32 (den exact <= 2048 < 2^24; num rel-err ~1e-4) ----
    #pragma unroll
    for (int off = 32; off > 0; off >>= 1) {
        num += __shfl_xor(num, off);
        den += __shfl_xor(den, off);
    }
    if (lane == 0) {
        partials[wv] = make_float2(num, den);
    }
}

__global__ __launch_bounds__(512) void eikonal_finalize(
        const float2* __restrict__ partials, float* __restrict__ out) {
    int t = threadIdx.x;
    double n = 0.0, d = 0.0;
    #pragma unroll
    for (int k = 0; k < NWAVE_ / 512; ++k) {
        float2 p = partials[t + (k << 9)];
        n += (double)p.x;
        d += (double)p.y;
    }
    #pragma unroll
    for (int off = 32; off > 0; off >>= 1) {
        n += __shfl_down(n, off);
        d += __shfl_down(d, off);
    }
    __shared__ double sn[8], sd[8];
    int wid = t >> 6;
    int lane = t & 63;
    if (lane == 0) { sn[wid] = n; sd[wid] = d; }
    __syncthreads();
    if (t == 0) {
        double fn = 0.0, fd = 0.0;
        #pragma unroll
        for (int k = 0; k < 8; ++k) { fn += sn[k]; fd += sd[k]; }
        if (fd < 1e-8) fd = 1e-8;
        out[0] = (float)(fn / fd);
    }
}

extern "C" void kernel_launch(void* const* d_in, const int* in_sizes, int n_in,
                              void* d_out, int out_size, void* d_ws, size_t ws_size,
                              hipStream_t stream) {
    const float* pred  = (const float*)d_in[0];
    const float* reach = (const float*)d_in[1];
    float* out = (float*)d_out;
    float2* partials = (float2*)d_ws;   // 4096 * 8B = 32 KB, fully rewritten each call

    eikonal_main<<<NBLK_, TPB_, 0, stream>>>(pred, reach, partials);
    eikonal_finalize<<<1, 512, 0, stream>>>(partials, out);
}

// Round 17
// 23.935 us; speedup vs baseline: 3.0217x; 1.0232x over previous
//
#include <hip/hip_runtime.h>

#define B_  32
#define H_  512
#define W_  512
#define HW_ (H_ * W_)
#define NWAVE_ 4096            // 32 img * 128 row-quads; 2 waves per block
#define NBLK_ 2048
#define TPB_  128

typedef float f32x4 __attribute__((ext_vector_type(4)));

__device__ __forceinline__ float rcp_fast(float x) { return __builtin_amdgcn_rcpf(x); }

__device__ __forceinline__ f32x4 rcp4(f32x4 v) {
    f32x4 r;
    r.x = rcp_fast(v.x); r.y = rcp_fast(v.y);
    r.z = rcp_fast(v.z); r.w = rcp_fast(v.w);
    return r;
}

// s = (1e-6 + sd^2)^2  (sign-free -> shared between minus/plus stencils)
__device__ __forceinline__ f32x4 sq4(f32x4 sd) {
    f32x4 t = sd * sd + 1e-6f;
    return t * t;
}

// WENO3 reconstruct, w-form: result = w*(p0-p1) + p1, w = sMid/(sMid+2sOut).
__device__ __forceinline__ float core(float sOut, float sMid,
                                      float fMain, float fOut, float fPair) {
    float a    = fMain + fPair;                 // 2*p1
    float b    = fOut + fPair;
    float diff = fmaf(-0.5f, b, fMain);         // p0 - p1
    float den  = fmaf(2.0f, sOut, sMid);
    float w    = sMid * rcp_fast(den);
    return fmaf(w, diff, 0.5f * a);
}

__device__ __forceinline__ f32x4 coreV(f32x4 sOut, f32x4 sMid,
                                       f32x4 fMain, f32x4 fOut, f32x4 fPair) {
    f32x4 a    = fMain + fPair;
    f32x4 b    = fOut + fPair;
    f32x4 diff = fMain - 0.5f * b;
    f32x4 den  = sMid + 2.0f * sOut;
    f32x4 w    = sMid * rcp4(den);
    return w * diff + 0.5f * a;
}

__device__ __forceinline__ f32x4 gyV(f32x4 um, f32x4 up) {
    f32x4 g;
    g.x = fmaxf(fmaxf(um.x, -up.x), 0.0f);
    g.y = fmaxf(fmaxf(um.y, -up.y), 0.0f);
    g.z = fmaxf(fmaxf(um.z, -up.z), 0.0f);
    g.w = fmaxf(fmaxf(um.w, -up.w), 0.0f);
    return g;
}

// One full row (8 px/lane): x-direction WENO with sliding shared smoothness;
// y-direction gy precomputed.
__device__ __forceinline__ void row_process(
        f32x4 c0, f32x4 c1,
        f32x4 gy0, f32x4 gy1,
        f32x4 q0, f32x4 q1,
        int lane, float target, float lo, float hi,
        float& num, float& den) {
    float xm2 = __shfl_up(c1.z, 1);
    float xm1 = __shfl_up(c1.w, 1);
    float xp1 = __shfl_down(c0.x, 1);
    float xp2 = __shfl_down(c0.y, 1);
    if (lane == 0)  { xm2 = c0.x; xm1 = c0.x; }
    if (lane == 63) { xp1 = c1.w; xp2 = c1.w; }

    float D[11];
    D[0]  = xm1  - xm2;
    D[1]  = c0.x - xm1;
    D[2]  = c0.y - c0.x;
    D[3]  = c0.z - c0.y;
    D[4]  = c0.w - c0.z;
    D[5]  = c1.x - c0.w;
    D[6]  = c1.y - c1.x;
    D[7]  = c1.z - c1.y;
    D[8]  = c1.w - c1.z;
    D[9]  = xp1  - c1.w;
    D[10] = xp2  - xp1;

    float s[10];
    #pragma unroll
    for (int k = 0; k < 10; ++k) {
        float sd = D[k] - D[k + 1];
        float t = fmaf(sd, sd, 1e-6f);
        s[k] = t * t;
    }

    #pragma unroll
    for (int i = 0; i < 8; ++i) {
        float um = core(s[i],     s[i + 1], D[i + 1], D[i],     D[i + 2]);
        float up = core(s[i + 2], s[i + 1], D[i + 2], D[i + 3], D[i + 1]);
        float gx = fmaxf(fmaxf(um, -up), 0.0f);
        float gy = (i < 4) ? gy0[i] : gy1[i - 4];
        float q  = (i < 4) ? q0[i]  : q1[i - 4];

        float gmag = __builtin_amdgcn_sqrtf(fmaf(gx, gx, fmaf(gy, gy, 1e-8f)));
        float r  = gmag - target;
        float ar = fabsf(r);
        float pp = (ar < 0.01f) ? (50.0f * r * r) : (ar - 0.005f);
        bool  m  = (q > 0.5f) && (gmag >= lo) && (gmag <= hi);
        float sel = m ? 1.0f : 0.0f;
        num = fmaf(sel, pp, num);
        den += sel;
    }
}

__device__ __forceinline__ int clampy(int v) {
    return v < 0 ? 0 : (v > H_ - 1 ? H_ - 1 : v);
}

__global__ __launch_bounds__(TPB_) void eikonal_main(
        const float* __restrict__ pred, const float* __restrict__ reach,
        float2* __restrict__ partials) {
    const float target = 1.0f / sqrtf((float)(511 * 511 + 511 * 511));
    const float lo = 0.3f * target;
    const float hi = 5.0f * target;

    int t = threadIdx.x;
    int lane = t & 63;

    // XCD-bijective swizzle (2048 % 8 == 0); 2 waves/block
    int bswz = ((blockIdx.x & 7) << 8) + (blockIdx.x >> 3);
    int wv = __builtin_amdgcn_readfirstlane((bswz << 1) + (t >> 6)); // 0..4095
    int b  = wv >> 7;            // image
    int y0 = (wv & 127) << 2;    // wave owns rows y0..y0+3

    const float* brow = pred + b * HW_;
    const float* rrow = reach + b * HW_;
    int x0 = lane << 3;          // 8 px per lane

    const float* rA = brow + (clampy(y0 - 2) << 9) + x0;
    const float* rB = brow + (clampy(y0 - 1) << 9) + x0;
    const float* rC = brow + ((y0    ) << 9) + x0;
    const float* rD = brow + ((y0 + 1) << 9) + x0;
    const float* rE = brow + ((y0 + 2) << 9) + x0;
    const float* rF = brow + ((y0 + 3) << 9) + x0;
    const float* rG = brow + (clampy(y0 + 4) << 9) + x0;
    const float* rH = brow + (clampy(y0 + 5) << 9) + x0;
    const f32x4* qCp = (const f32x4*)(rrow + ((y0    ) << 9) + x0);
    const f32x4* qDp = (const f32x4*)(rrow + ((y0 + 1) << 9) + x0);
    const f32x4* qEp = (const f32x4*)(rrow + ((y0 + 2) << 9) + x0);
    const f32x4* qFp = (const f32x4*)(rrow + ((y0 + 3) << 9) + x0);

    // ---- GROUP 1 loads (issued first): pred A..F + reach C,D = 16 ----
    f32x4 pA0 = *(const f32x4*)(rA);  f32x4 pA1 = *(const f32x4*)(rA + 4);
    f32x4 pB0 = *(const f32x4*)(rB);  f32x4 pB1 = *(const f32x4*)(rB + 4);
    f32x4 pC0 = *(const f32x4*)(rC);  f32x4 pC1 = *(const f32x4*)(rC + 4);
    f32x4 pD0 = *(const f32x4*)(rD);  f32x4 pD1 = *(const f32x4*)(rD + 4);
    f32x4 pE0 = *(const f32x4*)(rE);  f32x4 pE1 = *(const f32x4*)(rE + 4);
    f32x4 pF0 = *(const f32x4*)(rF);  f32x4 pF1 = *(const f32x4*)(rF + 4);
    f32x4 qC0 = __builtin_nontemporal_load(qCp);
    f32x4 qC1 = __builtin_nontemporal_load(qCp + 1);
    f32x4 qD0 = __builtin_nontemporal_load(qDp);
    f32x4 qD1 = __builtin_nontemporal_load(qDp + 1);

    // ---- GROUP 2 loads (issued after): pred G,H + reach E,F = 8 ----
    f32x4 pG0 = *(const f32x4*)(rG);  f32x4 pG1 = *(const f32x4*)(rG + 4);
    f32x4 pH0 = *(const f32x4*)(rH);  f32x4 pH1 = *(const f32x4*)(rH + 4);
    f32x4 qE0 = __builtin_nontemporal_load(qEp);
    f32x4 qE1 = __builtin_nontemporal_load(qEp + 1);
    f32x4 qF0 = __builtin_nontemporal_load(qFp);
    f32x4 qF1 = __builtin_nontemporal_load(qFp + 1);

    // Pin ONLY group 1: compiler emits s_waitcnt vmcnt(8) here (8 younger
    // group-2 loads stay in flight under phase-1 compute).
    asm volatile("" ::
        "v"(pA0), "v"(pA1), "v"(pB0), "v"(pB1),
        "v"(pC0), "v"(pC1), "v"(pD0), "v"(pD1),
        "v"(pE0), "v"(pE1), "v"(pF0), "v"(pF1),
        "v"(qC0), "v"(qC1), "v"(qD0), "v"(qD1));
    __builtin_amdgcn_sched_barrier(0);

    // ================= PHASE 1: rows C, D =================
    f32x4 dBA0 = pB0 - pA0, dBA1 = pB1 - pA1;
    f32x4 dCB0 = pC0 - pB0, dCB1 = pC1 - pB1;
    f32x4 dDC0 = pD0 - pC0, dDC1 = pD1 - pC1;
    f32x4 dED0 = pE0 - pD0, dED1 = pE1 - pD1;
    f32x4 dFE0 = pF0 - pE0, dFE1 = pF1 - pE1;

    f32x4 s0_0 = sq4(dBA0 - dCB0), s0_1 = sq4(dBA1 - dCB1);
    f32x4 s1_0 = sq4(dCB0 - dDC0), s1_1 = sq4(dCB1 - dDC1);
    f32x4 s2_0 = sq4(dDC0 - dED0), s2_1 = sq4(dDC1 - dED1);
    f32x4 s3_0 = sq4(dED0 - dFE0), s3_1 = sq4(dED1 - dFE1);

    f32x4 gyC0 = gyV(coreV(s0_0, s1_0, dCB0, dBA0, dDC0),
                     coreV(s2_0, s1_0, dDC0, dED0, dCB0));
    f32x4 gyC1 = gyV(coreV(s0_1, s1_1, dCB1, dBA1, dDC1),
                     coreV(s2_1, s1_1, dDC1, dED1, dCB1));
    f32x4 gyD0 = gyV(coreV(s1_0, s2_0, dDC0, dCB0, dED0),
                     coreV(s3_0, s2_0, dED0, dFE0, dDC0));
    f32x4 gyD1 = gyV(coreV(s1_1, s2_1, dDC1, dCB1, dED1),
                     coreV(s3_1, s2_1, dED1, dFE1, dDC1));

    float num = 0.0f, den = 0.0f;

    row_process(pC0, pC1, gyC0, gyC1, qC0, qC1, lane, target, lo, hi, num, den);
    row_process(pD0, pD1, gyD0, gyD1, qD0, qD1, lane, target, lo, hi, num, den);

    // Pin group 2 here: by now its latency is hidden under phase-1 compute.
    asm volatile("" ::
        "v"(pG0), "v"(pG1), "v"(pH0), "v"(pH1),
        "v"(qE0), "v"(qE1), "v"(qF0), "v"(qF1));
    __builtin_amdgcn_sched_barrier(0);

    // ================= PHASE 2: rows E, F =================
    f32x4 dGF0 = pG0 - pF0, dGF1 = pG1 - pF1;
    f32x4 dHG0 = pH0 - pG0, dHG1 = pH1 - pG1;

    f32x4 s4_0 = sq4(dFE0 - dGF0), s4_1 = sq4(dFE1 - dGF1);
    f32x4 s5_0 = sq4(dGF0 - dHG0), s5_1 = sq4(dGF1 - dHG1);

    f32x4 gyE0 = gyV(coreV(s2_0, s3_0, dED0, dDC0, dFE0),
                     coreV(s4_0, s3_0, dFE0, dGF0, dED0));
    f32x4 gyE1 = gyV(coreV(s2_1, s3_1, dED1, dDC1, dFE1),
                     coreV(s4_1, s3_1, dFE1, dGF1, dED1));
    f32x4 gyF0 = gyV(coreV(s3_0, s4_0, dFE0, dED0, dGF0),
                     coreV(s5_0, s4_0, dGF0, dHG0, dFE0));
    f32x4 gyF1 = gyV(coreV(s3_1, s4_1, dFE1, dED1, dGF1),
                     coreV(s5_1, s4_1, dGF1, dHG1, dFE1));

    row_process(pE0, pE1, gyE0, gyE1, qE0, qE1, lane, target, lo, hi, num, den);
    row_process(pF0, pF1, gyF0, gyF1, qF0, qF1, lane, target, lo, hi, num, den);

    // ---- wave reduce in f32 (den exact <= 2048 < 2^24; num rel-err ~1e-4) ----
    #pragma unroll
    for (int off = 32; off > 0; off >>= 1) {
        num += __shfl_xor(num, off);
        den += __shfl_xor(den, off);
    }
    if (lane == 0) {
        partials[wv] = make_float2(num, den);
    }
}

__global__ __launch_bounds__(512) void eikonal_finalize(
        const float2* __restrict__ partials, float* __restrict__ out) {
    int t = threadIdx.x;
    double n = 0.0, d = 0.0;
    #pragma unroll
    for (int k = 0; k < NWAVE_ / 512; ++k) {
        float2 p = partials[t + (k << 9)];
        n += (double)p.x;
        d += (double)p.y;
    }
    #pragma unroll
    for (int off = 32; off > 0; off >>= 1) {
        n += __shfl_down(n, off);
        d += __shfl_down(d, off);
    }
    __shared__ double sn[8], sd[8];
    int wid = t >> 6;
    int lane = t & 63;
    if (lane == 0) { sn[wid] = n; sd[wid] = d; }
    __syncthreads();
    if (t == 0) {
        double fn = 0.0, fd = 0.0;
        #pragma unroll
        for (int k = 0; k < 8; ++k) { fn += sn[k]; fd += sd[k]; }
        if (fd < 1e-8) fd = 1e-8;
        out[0] = (float)(fn / fd);
    }
}

extern "C" void kernel_launch(void* const* d_in, const int* in_sizes, int n_in,
                              void* d_out, int out_size, void* d_ws, size_t ws_size,
                              hipStream_t stream) {
    const float* pred  = (const float*)d_in[0];
    const float* reach = (const float*)d_in[1];
    float* out = (float*)d_out;
    float2* partials = (float2*)d_ws;   // 4096 * 8B = 32 KB, fully rewritten each call

    eikonal_main<<<NBLK_, TPB_, 0, stream>>>(pred, reach, partials);
    eikonal_finalize<<<1, 512, 0, stream>>>(partials, out);
}